// Round 2
// baseline (517.768 us; speedup 1.0000x reference)
//
#include <hip/hip_runtime.h>

typedef __bf16 bf16;
typedef __attribute__((ext_vector_type(8))) __bf16 bf16x8;
typedef __attribute__((ext_vector_type(4))) float f32x4;
typedef __attribute__((ext_vector_type(8))) unsigned short ushort8;   // 16B
typedef __attribute__((ext_vector_type(4))) unsigned short ushort4v;  // 8B

__device__ __forceinline__ unsigned short f2bf(float f) {
    union { float f; unsigned int u; } v; v.f = f;
    unsigned int u = v.u;
    return (unsigned short)((u + 0x7fffu + ((u >> 16) & 1u)) >> 16);
}

__device__ __forceinline__ f32x4 mfma16(bf16x8 a, bf16x8 b, f32x4 c) {
    return __builtin_amdgcn_mfma_f32_16x16x32_bf16(a, b, c, 0, 0, 0);
}

// ---------------- fp32 -> bf16 convert ----------------
__global__ void cvt_f32_bf16(const float* __restrict__ in, unsigned short* __restrict__ out, int n4) {
    int i = blockIdx.x * 256 + threadIdx.x;
    if (i >= n4) return;
    float4 f = reinterpret_cast<const float4*>(in)[i];
    ushort4v o;
    o.x = f2bf(f.x); o.y = f2bf(f.y); o.z = f2bf(f.z); o.w = f2bf(f.w);
    reinterpret_cast<ushort4v*>(out)[i] = o;
}

// ---------------- QKV GEMM: [8192x768] x [2304x768]^T, scatter to Q,K,Vt ----------------
// 128x128 tile, BK=32, 256 thr = 4 waves in 2x2, each wave 64x64 via 4x4 of 16x16x32 MFMA.
__global__ __launch_bounds__(256) void qkv_gemm(const unsigned short* __restrict__ A,
                                                const unsigned short* __restrict__ W,
                                                unsigned short* __restrict__ Qg,
                                                unsigned short* __restrict__ Kg,
                                                unsigned short* __restrict__ Vtg) {
    __shared__ __align__(16) unsigned short As[128 * 40];  // +8 pad: kill bank conflicts
    __shared__ __align__(16) unsigned short Bs[128 * 40];
    const int t = threadIdx.x;
    const int w = t >> 6, l = t & 63;
    const int wm = (w >> 1) * 64, wn = (w & 1) * 64;
    const int lr = l & 15, lq = l >> 4;
    const int m0 = blockIdx.y * 128, n0 = blockIdx.x * 128;
    f32x4 acc[4][4] = {};
    for (int k0 = 0; k0 < 768; k0 += 32) {
        __syncthreads();
#pragma unroll
        for (int i = 0; i < 2; ++i) {
            int v = t + i * 256;
            int r = v >> 2, c8 = (v & 3) * 8;
            *reinterpret_cast<ushort8*>(&As[r * 40 + c8]) =
                *reinterpret_cast<const ushort8*>(&A[(m0 + r) * 768 + k0 + c8]);
            *reinterpret_cast<ushort8*>(&Bs[r * 40 + c8]) =
                *reinterpret_cast<const ushort8*>(&W[(n0 + r) * 768 + k0 + c8]);
        }
        __syncthreads();
        bf16x8 af[4], bfr[4];
#pragma unroll
        for (int mt = 0; mt < 4; ++mt)
            af[mt] = *reinterpret_cast<const bf16x8*>(&As[(wm + mt * 16 + lr) * 40 + lq * 8]);
#pragma unroll
        for (int nt = 0; nt < 4; ++nt)
            bfr[nt] = *reinterpret_cast<const bf16x8*>(&Bs[(wn + nt * 16 + lr) * 40 + lq * 8]);
#pragma unroll
        for (int mt = 0; mt < 4; ++mt)
#pragma unroll
            for (int nt = 0; nt < 4; ++nt)
                acc[mt][nt] = mfma16(af[mt], bfr[nt], acc[mt][nt]);
    }
    // epilogue: o = tsel*768 + h*96 + d ; scatter (Q pre-scaled by 96^-0.5, V transposed)
#pragma unroll
    for (int nt = 0; nt < 4; ++nt) {
        int gn = n0 + wn + nt * 16 + lr;
        int tsel = gn / 768, rem = gn - tsel * 768;
        int h = rem / 96, d = rem - h * 96;
#pragma unroll
        for (int mt = 0; mt < 4; ++mt) {
#pragma unroll
            for (int r = 0; r < 4; ++r) {
                int gm = m0 + wm + mt * 16 + lq * 4 + r;
                int b = gm >> 12, n = gm & 4095;
                int bh = b * 8 + h;
                float val = acc[mt][nt][r];
                if (tsel == 0)      Qg[(bh * 4096 + n) * 96 + d] = f2bf(val * 0.10206207261596575f);
                else if (tsel == 1) Kg[(bh * 4096 + n) * 96 + d] = f2bf(val);
                else                Vtg[(bh * 96 + d) * 4096 + n] = f2bf(val);
            }
        }
    }
}

// ---------------- Flash attention: Br=128 (4 waves x 32 rows), Tc=64, D=96 ----------------
__global__ __launch_bounds__(256) void attn_kernel(const unsigned short* __restrict__ Qg,
                                                   const unsigned short* __restrict__ Kg,
                                                   const unsigned short* __restrict__ Vtg,
                                                   unsigned short* __restrict__ Og) {
    __shared__ __align__(16) unsigned short Qs[128 * 96];   // 24576 B
    __shared__ __align__(16) unsigned short Ks[64 * 104];   // +8 pad
    __shared__ __align__(16) unsigned short Vs[96 * 72];    // +8 pad
    __shared__ __align__(16) unsigned short Ps[128 * 72];   // +8 pad
    const int t = threadIdx.x;
    const int w = t >> 6, l = t & 63;
    const int lr = l & 15, lq = l >> 4;
    const int bh = blockIdx.y;
    const int q0 = blockIdx.x * 128;
    const int qbase = bh * 4096 * 96;

    // stage Q tile
#pragma unroll
    for (int i = 0; i < 6; ++i) {
        int v = t + i * 256;
        int r = v / 12, c8 = (v % 12) * 8;
        *reinterpret_cast<ushort8*>(&Qs[r * 96 + c8]) =
            *reinterpret_cast<const ushort8*>(&Qg[qbase + (q0 + r) * 96 + c8]);
    }
    __syncthreads();
    // hoist Q A-fragments (loop-invariant): wave w owns rows w*32..w*32+31
    bf16x8 aq[2][3];
#pragma unroll
    for (int mt = 0; mt < 2; ++mt)
#pragma unroll
        for (int kq = 0; kq < 3; ++kq)
            aq[mt][kq] = *reinterpret_cast<const bf16x8*>(&Qs[(w * 32 + mt * 16 + lr) * 96 + kq * 32 + lq * 8]);

    f32x4 acc[2][6] = {};
    float m_i[2][4], l_i[2][4], alph[2][4];
#pragma unroll
    for (int mt = 0; mt < 2; ++mt)
#pragma unroll
        for (int r = 0; r < 4; ++r) { m_i[mt][r] = -1e30f; l_i[mt][r] = 0.f; }

    for (int kv0 = 0; kv0 < 4096; kv0 += 64) {
        __syncthreads();
        // stage K (64x96) and Vt (96x64)
#pragma unroll
        for (int i = 0; i < 3; ++i) {
            int v = t + i * 256;
            int r = v / 12, c8 = (v % 12) * 8;
            *reinterpret_cast<ushort8*>(&Ks[r * 104 + c8]) =
                *reinterpret_cast<const ushort8*>(&Kg[qbase + (kv0 + r) * 96 + c8]);
            int d = v >> 3, c8v = (v & 7) * 8;
            *reinterpret_cast<ushort8*>(&Vs[d * 72 + c8v]) =
                *reinterpret_cast<const ushort8*>(&Vtg[(bh * 96 + d) * 4096 + kv0 + c8v]);
        }
        __syncthreads();
        // S = Q K^T   (Q carries the 96^-0.5 scale)
        f32x4 s[2][4] = {};
#pragma unroll
        for (int kq = 0; kq < 3; ++kq) {
            bf16x8 bk[4];
#pragma unroll
            for (int nt = 0; nt < 4; ++nt)
                bk[nt] = *reinterpret_cast<const bf16x8*>(&Ks[(nt * 16 + lr) * 104 + kq * 32 + lq * 8]);
#pragma unroll
            for (int mt = 0; mt < 2; ++mt)
#pragma unroll
                for (int nt = 0; nt < 4; ++nt)
                    s[mt][nt] = mfma16(aq[mt][kq], bk[nt], s[mt][nt]);
        }
        // online softmax: row = w*32 + mt*16 + lq*4 + r, cols spread over 16 lanes (lr)
#pragma unroll
        for (int mt = 0; mt < 2; ++mt) {
#pragma unroll
            for (int r = 0; r < 4; ++r) {
                float mx = fmaxf(fmaxf(s[mt][0][r], s[mt][1][r]), fmaxf(s[mt][2][r], s[mt][3][r]));
                mx = fmaxf(mx, __shfl_xor(mx, 1));
                mx = fmaxf(mx, __shfl_xor(mx, 2));
                mx = fmaxf(mx, __shfl_xor(mx, 4));
                mx = fmaxf(mx, __shfl_xor(mx, 8));
                float mnew = fmaxf(m_i[mt][r], mx);
                float a = __expf(m_i[mt][r] - mnew);
                float rs = 0.f;
                int prow = w * 32 + mt * 16 + lq * 4 + r;
#pragma unroll
                for (int nt = 0; nt < 4; ++nt) {
                    float p = __expf(s[mt][nt][r] - mnew);
                    rs += p;
                    Ps[prow * 72 + nt * 16 + lr] = f2bf(p);  // C-layout -> LDS (A-layout read below)
                }
                rs += __shfl_xor(rs, 1);
                rs += __shfl_xor(rs, 2);
                rs += __shfl_xor(rs, 4);
                rs += __shfl_xor(rs, 8);
                l_i[mt][r] = l_i[mt][r] * a + rs;
                m_i[mt][r] = mnew;
                alph[mt][r] = a;
            }
        }
        // rescale accumulator (C-layout rows match alpha's (lq,r) mapping)
#pragma unroll
        for (int mt = 0; mt < 2; ++mt)
#pragma unroll
            for (int dt = 0; dt < 6; ++dt)
#pragma unroll
                for (int r = 0; r < 4; ++r)
                    acc[mt][dt][r] *= alph[mt][r];
        // O += P V   (V as Vt rows => same A.B^T fragment pattern; P read back in A-layout)
#pragma unroll
        for (int kp = 0; kp < 2; ++kp) {
            bf16x8 bv[6];
#pragma unroll
            for (int dt = 0; dt < 6; ++dt)
                bv[dt] = *reinterpret_cast<const bf16x8*>(&Vs[(dt * 16 + lr) * 72 + kp * 32 + lq * 8]);
#pragma unroll
            for (int mt = 0; mt < 2; ++mt) {
                bf16x8 ap = *reinterpret_cast<const bf16x8*>(&Ps[(w * 32 + mt * 16 + lr) * 72 + kp * 32 + lq * 8]);
#pragma unroll
                for (int dt = 0; dt < 6; ++dt)
                    acc[mt][dt] = mfma16(ap, bv[dt], acc[mt][dt]);
            }
        }
    }
    // epilogue: normalize, write attn_out[b][n][h*96+d]  (bf16 scratch)
    const int b = bh >> 3, h = bh & 7;
#pragma unroll
    for (int mt = 0; mt < 2; ++mt) {
#pragma unroll
        for (int r = 0; r < 4; ++r) {
            float inv = 1.f / l_i[mt][r];
            int n = q0 + w * 32 + mt * 16 + lq * 4 + r;
            int rowoff = (b * 4096 + n) * 768 + h * 96;
#pragma unroll
            for (int dt = 0; dt < 6; ++dt)
                Og[rowoff + dt * 16 + lr] = f2bf(acc[mt][dt][r] * inv);
        }
    }
}

// ---------------- proj GEMM: [8192x768] x [768x768]^T -> FP32 out (d_out is float!) ----------------
__global__ __launch_bounds__(256) void proj_gemm(const unsigned short* __restrict__ A,
                                                 const unsigned short* __restrict__ W,
                                                 float* __restrict__ out) {
    __shared__ __align__(16) unsigned short As[128 * 40];
    __shared__ __align__(16) unsigned short Bs[128 * 40];
    const int t = threadIdx.x;
    const int w = t >> 6, l = t & 63;
    const int wm = (w >> 1) * 64, wn = (w & 1) * 64;
    const int lr = l & 15, lq = l >> 4;
    const int m0 = blockIdx.y * 128, n0 = blockIdx.x * 128;
    f32x4 acc[4][4] = {};
    for (int k0 = 0; k0 < 768; k0 += 32) {
        __syncthreads();
#pragma unroll
        for (int i = 0; i < 2; ++i) {
            int v = t + i * 256;
            int r = v >> 2, c8 = (v & 3) * 8;
            *reinterpret_cast<ushort8*>(&As[r * 40 + c8]) =
                *reinterpret_cast<const ushort8*>(&A[(m0 + r) * 768 + k0 + c8]);
            *reinterpret_cast<ushort8*>(&Bs[r * 40 + c8]) =
                *reinterpret_cast<const ushort8*>(&W[(n0 + r) * 768 + k0 + c8]);
        }
        __syncthreads();
        bf16x8 af[4], bfr[4];
#pragma unroll
        for (int mt = 0; mt < 4; ++mt)
            af[mt] = *reinterpret_cast<const bf16x8*>(&As[(wm + mt * 16 + lr) * 40 + lq * 8]);
#pragma unroll
        for (int nt = 0; nt < 4; ++nt)
            bfr[nt] = *reinterpret_cast<const bf16x8*>(&Bs[(wn + nt * 16 + lr) * 40 + lq * 8]);
#pragma unroll
        for (int mt = 0; mt < 4; ++mt)
#pragma unroll
            for (int nt = 0; nt < 4; ++nt)
                acc[mt][nt] = mfma16(af[mt], bfr[nt], acc[mt][nt]);
    }
#pragma unroll
    for (int nt = 0; nt < 4; ++nt) {
        int gn = n0 + wn + nt * 16 + lr;
#pragma unroll
        for (int mt = 0; mt < 4; ++mt) {
#pragma unroll
            for (int r = 0; r < 4; ++r) {
                int gm = m0 + wm + mt * 16 + lq * 4 + r;
                out[gm * 768 + gn] = acc[mt][nt][r];   // fp32 store
            }
        }
    }
}

extern "C" void kernel_launch(void* const* d_in, const int* in_sizes, int n_in,
                              void* d_out, int out_size, void* d_ws, size_t ws_size,
                              hipStream_t stream) {
    const float* x     = (const float*)d_in[0];   // [2,4096,768] fp32
    const float* wqkv  = (const float*)d_in[1];   // [2304,768] fp32
    const float* wproj = (const float*)d_in[2];   // [768,768] fp32
    float* out = (float*)d_out;                   // fp32 [2,4096,768]
    char* ws = (char*)d_ws;
    // workspace layout (bytes, all 16B aligned). attnb aliases xb (xb dead after qkv_gemm).
    unsigned short* xb     = (unsigned short*)(ws);             // 12582912
    unsigned short* wqkvb  = (unsigned short*)(ws + 12582912);  // 3538944
    unsigned short* wprojb = (unsigned short*)(ws + 16121856);  // 1179648
    unsigned short* Qg     = (unsigned short*)(ws + 17301504);  // 12582912  [B,H,N,D]
    unsigned short* Kg     = (unsigned short*)(ws + 29884416);  // 12582912  [B,H,N,D]
    unsigned short* Vtg    = (unsigned short*)(ws + 42467328);  // 12582912  [B,H,D,N]
    unsigned short* attnb  = xb;                                // reuse: [B,N,C] bf16

    cvt_f32_bf16<<<6144, 256, 0, stream>>>(x, xb, 1572864);
    cvt_f32_bf16<<<1728, 256, 0, stream>>>(wqkv, wqkvb, 442368);
    cvt_f32_bf16<<<576, 256, 0, stream>>>(wproj, wprojb, 147456);
    qkv_gemm<<<dim3(18, 64), 256, 0, stream>>>(xb, wqkvb, Qg, Kg, Vtg);
    attn_kernel<<<dim3(32, 16), 256, 0, stream>>>(Qg, Kg, Vtg, attnb);
    proj_gemm<<<dim3(6, 64), 256, 0, stream>>>(attnb, wprojb, out);
}

// Round 3
// 328.976 us; speedup vs baseline: 1.5739x; 1.5739x over previous
//
#include <hip/hip_runtime.h>

typedef __bf16 bf16;
typedef __attribute__((ext_vector_type(8))) __bf16 bf16x8;
typedef __attribute__((ext_vector_type(4))) float f32x4;
typedef __attribute__((ext_vector_type(8))) unsigned short ushort8;   // 16B
typedef __attribute__((ext_vector_type(4))) unsigned short ushort4v;  // 8B

__device__ __forceinline__ unsigned short f2bf(float f) {
    union { float f; unsigned int u; } v; v.f = f;
    unsigned int u = v.u;
    return (unsigned short)((u + 0x7fffu + ((u >> 16) & 1u)) >> 16);
}

__device__ __forceinline__ f32x4 mfma16(bf16x8 a, bf16x8 b, f32x4 c) {
    return __builtin_amdgcn_mfma_f32_16x16x32_bf16(a, b, c, 0, 0, 0);
}

// ---------------- fp32 -> bf16 convert ----------------
__global__ void cvt_f32_bf16(const float* __restrict__ in, unsigned short* __restrict__ out, int n4) {
    int i = blockIdx.x * 256 + threadIdx.x;
    if (i >= n4) return;
    float4 f = reinterpret_cast<const float4*>(in)[i];
    ushort4v o;
    o.x = f2bf(f.x); o.y = f2bf(f.y); o.z = f2bf(f.z); o.w = f2bf(f.w);
    reinterpret_cast<ushort4v*>(out)[i] = o;
}

// ---------------- QKV GEMM: [8192x768] x [2304x768]^T, scatter to Q,K,Vt ----------------
// Q is pre-scaled by SCALE*log2(e) so attention can use exp2 directly.
__global__ __launch_bounds__(256) void qkv_gemm(const unsigned short* __restrict__ A,
                                                const unsigned short* __restrict__ W,
                                                unsigned short* __restrict__ Qg,
                                                unsigned short* __restrict__ Kg,
                                                unsigned short* __restrict__ Vtg) {
    __shared__ __align__(16) unsigned short As[128 * 40];
    __shared__ __align__(16) unsigned short Bs[128 * 40];
    const int t = threadIdx.x;
    const int w = t >> 6, l = t & 63;
    const int wm = (w >> 1) * 64, wn = (w & 1) * 64;
    const int lr = l & 15, lq = l >> 4;
    const int m0 = blockIdx.y * 128, n0 = blockIdx.x * 128;
    f32x4 acc[4][4] = {};
    for (int k0 = 0; k0 < 768; k0 += 32) {
        __syncthreads();
#pragma unroll
        for (int i = 0; i < 2; ++i) {
            int v = t + i * 256;
            int r = v >> 2, c8 = (v & 3) * 8;
            *reinterpret_cast<ushort8*>(&As[r * 40 + c8]) =
                *reinterpret_cast<const ushort8*>(&A[(m0 + r) * 768 + k0 + c8]);
            *reinterpret_cast<ushort8*>(&Bs[r * 40 + c8]) =
                *reinterpret_cast<const ushort8*>(&W[(n0 + r) * 768 + k0 + c8]);
        }
        __syncthreads();
        bf16x8 af[4], bfr[4];
#pragma unroll
        for (int mt = 0; mt < 4; ++mt)
            af[mt] = *reinterpret_cast<const bf16x8*>(&As[(wm + mt * 16 + lr) * 40 + lq * 8]);
#pragma unroll
        for (int nt = 0; nt < 4; ++nt)
            bfr[nt] = *reinterpret_cast<const bf16x8*>(&Bs[(wn + nt * 16 + lr) * 40 + lq * 8]);
#pragma unroll
        for (int mt = 0; mt < 4; ++mt)
#pragma unroll
            for (int nt = 0; nt < 4; ++nt)
                acc[mt][nt] = mfma16(af[mt], bfr[nt], acc[mt][nt]);
    }
    // epilogue: Q scaled by 96^-0.5 * log2(e) = 0.14724444; V transposed
#pragma unroll
    for (int nt = 0; nt < 4; ++nt) {
        int gn = n0 + wn + nt * 16 + lr;
        int tsel = gn / 768, rem = gn - tsel * 768;
        int h = rem / 96, d = rem - h * 96;
#pragma unroll
        for (int mt = 0; mt < 4; ++mt) {
#pragma unroll
            for (int r = 0; r < 4; ++r) {
                int gm = m0 + wm + mt * 16 + lq * 4 + r;
                int b = gm >> 12, n = gm & 4095;
                int bh = b * 8 + h;
                float val = acc[mt][nt][r];
                if (tsel == 0)      Qg[(bh * 4096 + n) * 96 + d] = f2bf(val * 0.14724444f);
                else if (tsel == 1) Kg[(bh * 4096 + n) * 96 + d] = f2bf(val);
                else                Vtg[(bh * 96 + d) * 4096 + n] = f2bf(val);
            }
        }
    }
}

// ---------------- Flash attention (no-max streaming softmax, exp2 domain) ----------------
// Br=128 (4 waves x 32 rows), Tc=64, D=96.
// S^T via swapped MFMA operands -> P written with ds_write_b64; row-sum l via ones-B MFMA.
__global__ __launch_bounds__(256) void attn_kernel(const unsigned short* __restrict__ Qg,
                                                   const unsigned short* __restrict__ Kg,
                                                   const unsigned short* __restrict__ Vtg,
                                                   unsigned short* __restrict__ Og) {
    __shared__ __align__(16) unsigned short Qs[128 * 96];   // 24576 B
    __shared__ __align__(16) unsigned short Ks[64 * 104];   // +8 pad
    __shared__ __align__(16) unsigned short Vs[96 * 72];    // +8 pad
    __shared__ __align__(16) unsigned short Ps[128 * 72];   // +8 pad
    const int t = threadIdx.x;
    const int w = t >> 6, l = t & 63;
    const int lr = l & 15, lq = l >> 4;
    const int bh = blockIdx.y;
    const int q0 = blockIdx.x * 128;
    const int qbase = bh * 4096 * 96;

    // stage Q tile
#pragma unroll
    for (int i = 0; i < 6; ++i) {
        int v = t + i * 256;
        int r = v / 12, c8 = (v % 12) * 8;
        *reinterpret_cast<ushort8*>(&Qs[r * 96 + c8]) =
            *reinterpret_cast<const ushort8*>(&Qg[qbase + (q0 + r) * 96 + c8]);
    }
    __syncthreads();
    // hoist Q fragments (rows of Q; used as B-operand for S^T)
    bf16x8 aq[2][3];
#pragma unroll
    for (int mt = 0; mt < 2; ++mt)
#pragma unroll
        for (int kq = 0; kq < 3; ++kq)
            aq[mt][kq] = *reinterpret_cast<const bf16x8*>(&Qs[(w * 32 + mt * 16 + lr) * 96 + kq * 32 + lq * 8]);

    bf16x8 vones;
#pragma unroll
    for (int i = 0; i < 8; ++i) vones[i] = (__bf16)1.0f;

    f32x4 acc[2][6] = {};
    f32x4 acc_l[2] = {};

    for (int kv0 = 0; kv0 < 4096; kv0 += 64) {
        __syncthreads();
        // stage K (64x96) and Vt (96x64)
#pragma unroll
        for (int i = 0; i < 3; ++i) {
            int v = t + i * 256;
            int r = v / 12, c8 = (v % 12) * 8;
            *reinterpret_cast<ushort8*>(&Ks[r * 104 + c8]) =
                *reinterpret_cast<const ushort8*>(&Kg[qbase + (kv0 + r) * 96 + c8]);
            int d = v >> 3, c8v = (v & 7) * 8;
            *reinterpret_cast<ushort8*>(&Vs[d * 72 + c8v]) =
                *reinterpret_cast<const ushort8*>(&Vtg[(bh * 96 + d) * 4096 + kv0 + c8v]);
        }
        __syncthreads();
        // S^T = K Q^T (operands swapped): s[mt][nt][r] = S^T[key=nt*16+lq*4+r][qrow=w*32+mt*16+lr]
        f32x4 s[2][4] = {};
#pragma unroll
        for (int kq = 0; kq < 3; ++kq) {
            bf16x8 bk[4];
#pragma unroll
            for (int nt = 0; nt < 4; ++nt)
                bk[nt] = *reinterpret_cast<const bf16x8*>(&Ks[(nt * 16 + lr) * 104 + kq * 32 + lq * 8]);
#pragma unroll
            for (int mt = 0; mt < 2; ++mt)
#pragma unroll
                for (int nt = 0; nt < 4; ++nt)
                    s[mt][nt] = mfma16(bk[nt], aq[mt][kq], s[mt][nt]);
        }
        // p = exp2(s) (Q pre-scaled by log2e*scale); pack 4 consecutive keys -> one b64 store
#pragma unroll
        for (int mt = 0; mt < 2; ++mt) {
#pragma unroll
            for (int nt = 0; nt < 4; ++nt) {
                ushort4v pk;
#pragma unroll
                for (int r = 0; r < 4; ++r)
                    pk[r] = f2bf(__builtin_amdgcn_exp2f(s[mt][nt][r]));
                *reinterpret_cast<ushort4v*>(&Ps[(w * 32 + mt * 16 + lr) * 72 + nt * 16 + lq * 4]) = pk;
            }
        }
        __syncthreads();  // waves only touch their own Ps rows, but staging loop below rewrites Ks/Vs
        // O += P V ; l += P * ones (row-sum via MFMA, no shuffles)
#pragma unroll
        for (int kp = 0; kp < 2; ++kp) {
            bf16x8 bv[6];
#pragma unroll
            for (int dt = 0; dt < 6; ++dt)
                bv[dt] = *reinterpret_cast<const bf16x8*>(&Vs[(dt * 16 + lr) * 72 + kp * 32 + lq * 8]);
#pragma unroll
            for (int mt = 0; mt < 2; ++mt) {
                bf16x8 ap = *reinterpret_cast<const bf16x8*>(&Ps[(w * 32 + mt * 16 + lr) * 72 + kp * 32 + lq * 8]);
#pragma unroll
                for (int dt = 0; dt < 6; ++dt)
                    acc[mt][dt] = mfma16(ap, bv[dt], acc[mt][dt]);
                acc_l[mt] = mfma16(ap, vones, acc_l[mt]);
            }
        }
    }
    // epilogue: normalize, write attn_out[b][n][h*96+d]  (bf16 scratch)
    const int b = bh >> 3, h = bh & 7;
#pragma unroll
    for (int mt = 0; mt < 2; ++mt) {
#pragma unroll
        for (int r = 0; r < 4; ++r) {
            float inv = 1.f / acc_l[mt][r];
            int n = q0 + w * 32 + mt * 16 + lq * 4 + r;
            int rowoff = (b * 4096 + n) * 768 + h * 96;
#pragma unroll
            for (int dt = 0; dt < 6; ++dt)
                Og[rowoff + dt * 16 + lr] = f2bf(acc[mt][dt][r] * inv);
        }
    }
}

// ---------------- proj GEMM: [8192x768] x [768x768]^T -> FP32 out ----------------
__global__ __launch_bounds__(256) void proj_gemm(const unsigned short* __restrict__ A,
                                                 const unsigned short* __restrict__ W,
                                                 float* __restrict__ out) {
    __shared__ __align__(16) unsigned short As[128 * 40];
    __shared__ __align__(16) unsigned short Bs[128 * 40];
    const int t = threadIdx.x;
    const int w = t >> 6, l = t & 63;
    const int wm = (w >> 1) * 64, wn = (w & 1) * 64;
    const int lr = l & 15, lq = l >> 4;
    const int m0 = blockIdx.y * 128, n0 = blockIdx.x * 128;
    f32x4 acc[4][4] = {};
    for (int k0 = 0; k0 < 768; k0 += 32) {
        __syncthreads();
#pragma unroll
        for (int i = 0; i < 2; ++i) {
            int v = t + i * 256;
            int r = v >> 2, c8 = (v & 3) * 8;
            *reinterpret_cast<ushort8*>(&As[r * 40 + c8]) =
                *reinterpret_cast<const ushort8*>(&A[(m0 + r) * 768 + k0 + c8]);
            *reinterpret_cast<ushort8*>(&Bs[r * 40 + c8]) =
                *reinterpret_cast<const ushort8*>(&W[(n0 + r) * 768 + k0 + c8]);
        }
        __syncthreads();
        bf16x8 af[4], bfr[4];
#pragma unroll
        for (int mt = 0; mt < 4; ++mt)
            af[mt] = *reinterpret_cast<const bf16x8*>(&As[(wm + mt * 16 + lr) * 40 + lq * 8]);
#pragma unroll
        for (int nt = 0; nt < 4; ++nt)
            bfr[nt] = *reinterpret_cast<const bf16x8*>(&Bs[(wn + nt * 16 + lr) * 40 + lq * 8]);
#pragma unroll
        for (int mt = 0; mt < 4; ++mt)
#pragma unroll
            for (int nt = 0; nt < 4; ++nt)
                acc[mt][nt] = mfma16(af[mt], bfr[nt], acc[mt][nt]);
    }
#pragma unroll
    for (int nt = 0; nt < 4; ++nt) {
        int gn = n0 + wn + nt * 16 + lr;
#pragma unroll
        for (int mt = 0; mt < 4; ++mt) {
#pragma unroll
            for (int r = 0; r < 4; ++r) {
                int gm = m0 + wm + mt * 16 + lq * 4 + r;
                out[gm * 768 + gn] = acc[mt][nt][r];
            }
        }
    }
}

extern "C" void kernel_launch(void* const* d_in, const int* in_sizes, int n_in,
                              void* d_out, int out_size, void* d_ws, size_t ws_size,
                              hipStream_t stream) {
    const float* x     = (const float*)d_in[0];   // [2,4096,768] fp32
    const float* wqkv  = (const float*)d_in[1];   // [2304,768] fp32
    const float* wproj = (const float*)d_in[2];   // [768,768] fp32
    float* out = (float*)d_out;                   // fp32 [2,4096,768]
    char* ws = (char*)d_ws;
    unsigned short* xb     = (unsigned short*)(ws);             // 12582912
    unsigned short* wqkvb  = (unsigned short*)(ws + 12582912);  // 3538944
    unsigned short* wprojb = (unsigned short*)(ws + 16121856);  // 1179648
    unsigned short* Qg     = (unsigned short*)(ws + 17301504);  // [B,H,N,D]
    unsigned short* Kg     = (unsigned short*)(ws + 29884416);  // [B,H,N,D]
    unsigned short* Vtg    = (unsigned short*)(ws + 42467328);  // [B,H,D,N]
    unsigned short* attnb  = xb;                                // reuse: [B,N,C] bf16

    cvt_f32_bf16<<<6144, 256, 0, stream>>>(x, xb, 1572864);
    cvt_f32_bf16<<<1728, 256, 0, stream>>>(wqkv, wqkvb, 442368);
    cvt_f32_bf16<<<576, 256, 0, stream>>>(wproj, wprojb, 147456);
    qkv_gemm<<<dim3(18, 64), 256, 0, stream>>>(xb, wqkvb, Qg, Kg, Vtg);
    attn_kernel<<<dim3(32, 16), 256, 0, stream>>>(Qg, Kg, Vtg, attnb);
    proj_gemm<<<dim3(6, 64), 256, 0, stream>>>(attnb, wprojb, out);
}